// Round 2
// 203.858 us; speedup vs baseline: 1.0093x; 1.0093x over previous
//
#include <hip/hip_runtime.h>

// HyperedgeAggregator: out[s, :] = mean over members i with segment_ids[i]==s
// of node_embeddings[node_indices[i], :].
//
// NUM_NODES=100000, EMBED_DIM=256, NUM_EDGES=16384, TOTAL=524288.
// segment_ids is SORTED. Two-kernel plan:
//   1) seg_bounds_kernel: one pass over seg_ids -> seg_start[NUM_EDGES+1] in d_ws
//   2) hyperedge_agg_kernel: ONE BLOCK (4 waves) per segment. Members are
//      round-robined across the 4 waves (wave w takes members w, w+4, ...),
//      so a whole average segment (~32 rows) is in flight per block and the
//      per-wave serial chain is ~8 rows. Each wave keeps an 8-deep float4
//      pipeline in registers (unconditional static indexing -> stays in VGPRs,
//      ~60 VGPR -> 8 waves/SIMD). Partials combined via 4KB LDS, wave 0 writes.

#define EMBED_DIM 256
#define NUM_EDGES 16384
#define TOTAL_MEM 524288

__global__ __launch_bounds__(256) void seg_bounds_kernel(
    const int* __restrict__ seg_ids,   // [TOTAL_MEM], sorted ascending
    int*       __restrict__ seg_start) // [NUM_EDGES+1]
{
    const int i = blockIdx.x * blockDim.x + threadIdx.x;
    if (i >= TOTAL_MEM) return;
    const int cur  = seg_ids[i];
    const int prev = (i == 0) ? -1 : seg_ids[i - 1];
    for (int s = prev + 1; s <= cur; ++s) seg_start[s] = i;
    if (i == TOTAL_MEM - 1) {
        for (int s = cur + 1; s <= NUM_EDGES; ++s) seg_start[s] = TOTAL_MEM;
    }
}

__global__ __launch_bounds__(256) void hyperedge_agg_kernel(
    const float* __restrict__ emb,        // [NUM_NODES, EMBED_DIM]
    const int*   __restrict__ node_idx,   // [TOTAL_MEM]
    const int*   __restrict__ seg_start,  // [NUM_EDGES+1]
    float*       __restrict__ out)        // [NUM_EDGES, EMBED_DIM]
{
    __shared__ float4 partial[4][64];     // 4 KB

    const int wave = threadIdx.x >> 6;    // 4 waves, one segment per block
    const int lane = threadIdx.x & 63;
    const int seg  = blockIdx.x;

    const int start = seg_start[seg];
    const int end   = seg_start[seg + 1];

    float4 acc = make_float4(0.f, 0.f, 0.f, 0.f);

    for (int base = start; base < end; base += 64) {
        const int batch = min(end - base, 64);
        // coalesced batch load of member indices; one per lane, shared by all
        // 4 waves of the block (L1-hit after the first wave's load)
        const int my = (lane < batch) ? node_idx[base + lane] : 0;
        // this wave's members: t = wave, wave+4, wave+8, ... < batch
        const int nMine = (batch > wave) ? ((batch - wave + 3) >> 2) : 0;

        float4 v[8];
        const int m0 = min(nMine, 8);

        // issue up to 8 row loads back-to-back (static indices -> registers)
        #pragma unroll
        for (int t = 0; t < 8; ++t)
            if (t < m0) {
                const int n = __shfl(my, wave + (t << 2));
                v[t] = ((const float4*)(emb + (size_t)n * EMBED_DIM))[lane];
            }

        // rolling consume: eat v[t] (in issue order), reissue t+8 if present
        #pragma unroll
        for (int t = 0; t < 8; ++t) {
            if (t < m0) {
                const float4 u = v[t];
                const int t2 = t + 8;
                if (t2 < nMine) {
                    const int n = __shfl(my, wave + (t2 << 2));
                    v[t] = ((const float4*)(emb + (size_t)n * EMBED_DIM))[lane];
                }
                acc.x += u.x; acc.y += u.y; acc.z += u.z; acc.w += u.w;
            }
        }
        // consume the reissued tail (nMine in (8,16], i.e. batch > 32)
        #pragma unroll
        for (int t = 0; t < 8; ++t)
            if (t + 8 < nMine) {
                acc.x += v[t].x; acc.y += v[t].y;
                acc.z += v[t].z; acc.w += v[t].w;
            }
    }

    partial[wave][lane] = acc;
    __syncthreads();

    if (wave == 0) {
        const float4 a = partial[0][lane];
        const float4 b = partial[1][lane];
        const float4 c = partial[2][lane];
        const float4 d = partial[3][lane];
        float4 s;
        s.x = (a.x + b.x) + (c.x + d.x);
        s.y = (a.y + b.y) + (c.y + d.y);
        s.z = (a.z + b.z) + (c.z + d.z);
        s.w = (a.w + b.w) + (c.w + d.w);
        const float cnt = (end > start) ? (float)(end - start) : 1.0f;
        s.x /= cnt; s.y /= cnt; s.z /= cnt; s.w /= cnt;
        ((float4*)(out + (size_t)seg * EMBED_DIM))[lane] = s;
    }
}

// Fallback (no workspace): per-wave binary search.
__global__ __launch_bounds__(256) void hyperedge_agg_bsearch_kernel(
    const float* __restrict__ emb,
    const int*   __restrict__ node_idx,
    const int*   __restrict__ seg_ids,
    float*       __restrict__ out)
{
    const int wave = threadIdx.x >> 6;
    const int lane = threadIdx.x & 63;
    const int seg  = blockIdx.x * 4 + wave;
    if (seg >= NUM_EDGES) return;

    int lo = 0, hi = TOTAL_MEM;
    while (lo < hi) {
        int mid = (lo + hi) >> 1;
        if (seg_ids[mid] < seg) lo = mid + 1; else hi = mid;
    }
    const int start = lo;
    hi = TOTAL_MEM;
    while (lo < hi) {
        int mid = (lo + hi) >> 1;
        if (seg_ids[mid] < seg + 1) lo = mid + 1; else hi = mid;
    }
    const int end = lo;

    float4 acc = make_float4(0.f, 0.f, 0.f, 0.f);
    for (int i = start; i < end; ++i) {
        const int n = node_idx[i];
        float4 v = ((const float4*)(emb + (size_t)n * EMBED_DIM))[lane];
        acc.x += v.x; acc.y += v.y; acc.z += v.z; acc.w += v.w;
    }
    const float cnt = (end > start) ? (float)(end - start) : 1.0f;
    acc.x /= cnt; acc.y /= cnt; acc.z /= cnt; acc.w /= cnt;
    ((float4*)(out + (size_t)seg * EMBED_DIM))[lane] = acc;
}

extern "C" void kernel_launch(void* const* d_in, const int* in_sizes, int n_in,
                              void* d_out, int out_size, void* d_ws, size_t ws_size,
                              hipStream_t stream) {
    const float* emb      = (const float*)d_in[0];
    const int*   node_idx = (const int*)d_in[1];
    const int*   seg_ids  = (const int*)d_in[2];
    float*       out      = (float*)d_out;

    const size_t bounds_bytes = (size_t)(NUM_EDGES + 1) * sizeof(int);
    if (ws_size >= bounds_bytes) {
        int* seg_start = (int*)d_ws;
        seg_bounds_kernel<<<(TOTAL_MEM + 255) / 256, 256, 0, stream>>>(seg_ids, seg_start);
        hyperedge_agg_kernel<<<NUM_EDGES, 256, 0, stream>>>(emb, node_idx, seg_start, out);
    } else {
        hyperedge_agg_bsearch_kernel<<<NUM_EDGES / 4, 256, 0, stream>>>(emb, node_idx, seg_ids, out);
    }
}